// Round 11
// baseline (718.934 us; speedup 1.0000x reference)
//
#include <hip/hip_runtime.h>

#define T_TOK 8192
#define HDIM  2048
#define NEXP  32
#define IDIM  1024

#define BM 128
#define BN 128
#define BK 64
#define CAP (T_TOK*2 + NEXP*BM)   // 20480 max padded rows
#define MAX_RT (CAP/BM)           // 160 row tiles max
#define CVB 8192                  // cvt_hs blocks (256 thr x 8 elem)
#define NTB 2048                  // transpose pipeline blocks

typedef __attribute__((ext_vector_type(8))) short bh8;   // 8 bf16 (4 VGPR) MFMA A/B frag
typedef __attribute__((ext_vector_type(4))) float f4;    // MFMA C/D frag

// fp32 -> bf16 round-to-nearest-even (bit pattern)
__device__ __forceinline__ unsigned short f2bf(float f) {
    unsigned u = __builtin_bit_cast(unsigned, f);
    u += 0x7FFFu + ((u >> 16) & 1u);
    return (unsigned short)(u >> 16);
}

// XOR swizzle: 128-byte LDS rows, byte ^= (row&7)<<4.  (proven 0-conflict, rounds 1-2)
__device__ __forceinline__ int swz(int row, int kb) {
    return row * 128 + (kb ^ ((row & 7) << 4));
}

// async 16B global->LDS (dest = wave-uniform base, HW adds lane*16; source per-lane)
__device__ __forceinline__ void gload16(const void* g, void* l) {
    __builtin_amdgcn_global_load_lds(
        (const __attribute__((address_space(1))) unsigned int*)g,
        (__attribute__((address_space(3))) unsigned int*)l,
        16, 0, 0);
}

// ---------------- routing ----------------

__device__ __forceinline__ void top2(const float* __restrict__ l,
                                     int& b1, float& v1, int& b2, float& v2) {
    v1 = -1e30f; b1 = 0;
#pragma unroll
    for (int e = 0; e < NEXP; ++e) { float v = l[e]; if (v > v1) { v1 = v; b1 = e; } }
    v2 = -1e30f; b2 = 0;
#pragma unroll
    for (int e = 0; e < NEXP; ++e) { if (e == b1) continue; float v = l[e]; if (v > v2) { v2 = v; b2 = e; } }
}

__global__ void route_count_kernel(const float* __restrict__ logits, int* __restrict__ counts) {
    int t = blockIdx.x * blockDim.x + threadIdx.x;
    if (t >= T_TOK) return;
    int b1, b2; float v1, v2;
    top2(logits + (size_t)t * NEXP, b1, v1, b2, v2);
    atomicAdd(&counts[b1], 1);
    atomicAdd(&counts[b2], 1);
}

__global__ void offsets_kernel(const int* __restrict__ counts, int* __restrict__ offs) {
    if (threadIdx.x == 0) {
        int o = 0;
        for (int e = 0; e < NEXP; ++e) { offs[e] = o; o += (counts[e] + BM - 1) & ~(BM - 1); }
        offs[NEXP] = o;
    }
}

__global__ void route_scatter_kernel(const float* __restrict__ logits,
                                     const float* __restrict__ scale,
                                     const int* __restrict__ offs,
                                     int* __restrict__ cursor,
                                     int* __restrict__ row_tok,
                                     float* __restrict__ row_w) {
    int t = blockIdx.x * blockDim.x + threadIdx.x;
    if (t >= T_TOK) return;
    int b1, b2; float v1, v2;
    top2(logits + (size_t)t * NEXP, b1, v1, b2, v2);
    float e2 = expf(v2 - v1);
    float inv = 1.0f / (1.0f + e2);
    float w1 = scale[b1] * inv;
    float w2 = scale[b2] * e2 * inv;
    int p1 = offs[b1] + atomicAdd(&cursor[b1], 1);
    row_tok[p1] = t; row_w[p1] = w1;
    int p2 = offs[b2] + atomicAdd(&cursor[b2], 1);
    row_tok[p2] = t; row_w[p2] = w2;
}

// ---------------- prep v4: pipelined gload16 transpose+convert ----------------
// 128x128 tile = two [64k][128n] fp32 halves (32 KB each), double-buffered LDS.
// Per half-iter: issue DMA(next half) -> phase2(cur: ds_read + cvt + store) ->
// ONE barrier (vmcnt drain lands after ~1400 cyc of phase-2).  [T3-minimum]
// Bank swizzle: 16B-chunk cc ^= (kg&7)<<2, applied on DMA SOURCE and on the read
// (rule 21: linear dest + inverse-swz source + swz read).

// DMA one [64][128] fp32 half into ldsH (linear chunks, pre-swizzled source).
__device__ __forceinline__ void half_dma(const float* __restrict__ in, int K, int N,
                                         int e, int k0, int n0, char* ldsH, int t) {
    const char* src = (const char*)(in + (size_t)e * K * N + (size_t)k0 * N + n0);
    int w = t >> 6;
#pragma unroll
    for (int i = 0; i < 8; ++i) {
        int c = i * 256 + t;                        // chunk 0..2047
        int k = c >> 5;                             // 0..63
        int cc = (c & 31) ^ (((k >> 3) & 7) << 2);  // pre-swizzled source chunk
        gload16(src + (size_t)k * N * 4 + (size_t)cc * 16, ldsH + i * 4096 + w * 1024);
    }
}

// convert + store one half: thread (kg=t&7, nb=t>>3), 4 passes over n.
// writes: 8 lanes x 16B = 128B contiguous dst row segments.
__device__ __forceinline__ void half_store(unsigned short* __restrict__ out, int K, int N,
                                           int e, int k0, int n0, const char* ldsH, int t) {
    unsigned short* dst = out + (size_t)e * K * N + (size_t)n0 * K + k0;
    int kg = t & 7, nb = t >> 3;
#pragma unroll
    for (int p = 0; p < 4; ++p) {
        int n = nb + 32 * p;
        bh8 v;
#pragma unroll
        for (int j = 0; j < 8; ++j) {
            int kl = 8 * kg + j;
            int boff = kl * 512 + ((((n >> 2) ^ ((kg & 7) << 2)) << 4)) + (n & 3) * 4;
            v[j] = (short)f2bf(*(const float*)(ldsH + boff));
        }
        *(bh8*)(dst + (size_t)n * K + 8 * kg) = v;
    }
}

// g in [0, nTiles): mat = g>>12 (4096 tiles per matrix: 32 experts x 128 tiles)
__device__ __forceinline__ void tile_params(int g,
                                            const float* wg, const float* wu, const float* wd,
                                            unsigned short* wgT, unsigned short* wuT, unsigned short* wdT,
                                            const float*& in, unsigned short*& out,
                                            int& K, int& N, int& e, int& k0, int& n0) {
    int mat = g >> 12;
    int loc = g & 4095;
    e = loc >> 7;
    int tl = loc & 127;
    if (mat == 2) { in = wd; out = wdT; K = IDIM; N = HDIM; k0 = (tl >> 4) << 7; n0 = (tl & 15) << 7; }
    else if (mat == 1) { in = wu; out = wuT; K = HDIM; N = IDIM; k0 = (tl >> 3) << 7; n0 = (tl & 7) << 7; }
    else { in = wg; out = wgT; K = HDIM; N = IDIM; k0 = (tl >> 3) << 7; n0 = (tl & 7) << 7; }
}

// Fused: cvt_hs (blocks [0,CVB)) | pipelined transposes (blocks [CVB, CVB+NTB)).
__global__ void prep_all(const float* __restrict__ hs, unsigned short* __restrict__ hsb,
                         const float* __restrict__ wg, unsigned short* __restrict__ wgT,
                         const float* __restrict__ wu, unsigned short* __restrict__ wuT,
                         const float* __restrict__ wd, unsigned short* __restrict__ wdT,
                         int nTiles) {
    __shared__ float lds4[16384];   // 64 KB = 2 x 32 KB halves
    int b = blockIdx.x;
    int t = threadIdx.x;
    if (b < CVB) {
        size_t i = ((size_t)b * 256 + t) * 8;
        float4 a = *(const float4*)(hs + i);
        float4 c = *(const float4*)(hs + i + 4);
        bh8 v;
        v[0] = (short)f2bf(a.x); v[1] = (short)f2bf(a.y);
        v[2] = (short)f2bf(a.z); v[3] = (short)f2bf(a.w);
        v[4] = (short)f2bf(c.x); v[5] = (short)f2bf(c.y);
        v[6] = (short)f2bf(c.z); v[7] = (short)f2bf(c.w);
        *(bh8*)(hsb + i) = v;
        return;
    }
    int tb = b - CVB;
    char* L0 = (char*)lds4;
    char* L1 = L0 + 32768;
    int nq = nTiles / NTB;

    // prologue: DMA (q=0, hh=0) into L0
    {
        const float* in; unsigned short* o; int K, N, e, k0, n0;
        tile_params(tb, wg, wu, wd, wgT, wuT, wdT, in, o, K, N, e, k0, n0);
        half_dma(in, K, N, e, k0, n0, L0, t);
    }
    __syncthreads();

    int cur = 0;
    for (int q = 0; q < nq; ++q) {
        const float* in; unsigned short* o; int K, N, e, k0, n0;
        tile_params(tb + q * NTB, wg, wu, wd, wgT, wuT, wdT, in, o, K, N, e, k0, n0);
#pragma unroll
        for (int hh = 0; hh < 2; ++hh) {
            int nq2 = q, nh = hh + 1;
            if (nh == 2) { nq2 = q + 1; nh = 0; }
            if (nq2 < nq) {
                const float* in2; unsigned short* o2; int K2, N2, e2, k02, n02;
                tile_params(tb + nq2 * NTB, wg, wu, wd, wgT, wuT, wdT, in2, o2, K2, N2, e2, k02, n02);
                half_dma(in2, K2, N2, e2, k02 + nh * 64, n02, cur ? L0 : L1, t);
            }
            half_store(o, K, N, e, k0 + hh * 64, n0, cur ? L1 : L0, t);
            __syncthreads();
            cur ^= 1;
        }
    }
}

// standalone wd transpose (serial fallback path): 2048 blocks x 2 tiles, same pipeline
__global__ void transpose_wd_kernel(const float* __restrict__ wd, unsigned short* __restrict__ wdT) {
    __shared__ float lds4[16384];
    int tb = blockIdx.x, t = threadIdx.x;
    char* L0 = (char*)lds4;
    char* L1 = L0 + 32768;
    // wd-only params: g in [0,4096)
    auto prm = [&](int g, int& e, int& k0, int& n0) {
        e = g >> 7; int tl = g & 127;
        k0 = (tl >> 4) << 7; n0 = (tl & 15) << 7;
    };
    int e, k0, n0;
    prm(tb, e, k0, n0);
    half_dma(wd, IDIM, HDIM, e, k0, n0, L0, t);
    __syncthreads();
    int cur = 0;
    for (int q = 0; q < 2; ++q) {
        int eq, kq, nq0;
        prm(tb + q * NTB, eq, kq, nq0);
#pragma unroll
        for (int hh = 0; hh < 2; ++hh) {
            int q2 = q, nh = hh + 1;
            if (nh == 2) { q2 = q + 1; nh = 0; }
            if (q2 < 2) {
                int e2, k2, n2;
                prm(tb + q2 * NTB, e2, k2, n2);
                half_dma(wd, IDIM, HDIM, e2, k2 + nh * 64, n2, cur ? L0 : L1, t);
            }
            half_store(wdT, IDIM, HDIM, eq, kq + hh * 64, nq0, cur ? L1 : L0, t);
            __syncthreads();
            cur ^= 1;
        }
    }
}

// ============ GEMM1 (round-2 proven body, byte-identical) ============
// 128 rows x 128 cols(G)+128(U), waves 2x2 (64x64 each). All operands bf16 via
// gload16, pre-swizzled sources, zero-conflict LDS. 49 KB -> 3 blocks/CU.
__launch_bounds__(256, 2)
__global__ void gemm1n_kernel(const unsigned short* __restrict__ hsb,
                              const unsigned short* __restrict__ wgT,
                              const unsigned short* __restrict__ wuT,
                              const int* __restrict__ offs,
                              const int* __restrict__ row_tok,
                              unsigned short* __restrict__ act) {
    __shared__ char lds[49152];
    char* Xb = lds;
    char* Gb = lds + 16384;
    char* Ub = lds + 32768;

    int rt = blockIdx.x >> 3;
    int nt = blockIdx.x & 7;
    int total = offs[NEXP];
    if (rt * BM >= total) return;
    int e = 0;
    while (offs[e + 1] <= rt * BM) e++;

    int tid = threadIdx.x, l = tid & 63, wv = tid >> 6;
    int wm = wv >> 1, wn = wv & 1;

    unsigned srcChunk = ((l & 7) * 16) ^ ((l >> 3) << 4);

    unsigned xoff[4], goff[4];
#pragma unroll
    for (int i = 0; i < 4; ++i) {
        int r = i * 32 + wv * 8 + (l >> 3);
        int tok = row_tok[rt * BM + r];
        if (tok < 0) tok = 0;
        xoff[i] = (unsigned)tok * (HDIM * 2) + srcChunk;
        unsigned wrow = (unsigned)e * IDIM + nt * BN + r;
        goff[i] = wrow * (HDIM * 2) + srcChunk;
    }

    f4 accG[4][4], accU[4][4];
#pragma unroll
    for (int mi = 0; mi < 4; ++mi)
#pragma unroll
        for (int ni = 0; ni < 4; ++ni) { accG[mi][ni] = (f4)0.0f; accU[mi][ni] = (f4)0.0f; }

    const char* hsc = (const char*)hsb;
    const char* wgc = (const char*)wgT;
    const char* wuc = (const char*)wuT;

    for (int kt = 0; kt < HDIM / BK; ++kt) {
        unsigned kby = kt * 128;
#pragma unroll
        for (int i = 0; i < 4; ++i)
            gload16(hsc + (size_t)xoff[i] + kby, Xb + i * 4096 + wv * 1024);
#pragma unroll
        for (int i = 0; i < 4; ++i)
            gload16(wgc + (size_t)goff[i] + kby, Gb + i * 4096 + wv * 1024);
#pragma unroll
        for (int i = 0; i < 4; ++i)
            gload16(wuc + (size_t)goff[i] + kby, Ub + i * 4096 + wv * 1024);
        __syncthreads();

#pragma unroll
        for (int ks = 0; ks < 2; ++ks) {
            int kb = ks * 64 + ((l >> 4) << 4);
            bh8 a[4], g[4], u[4];
#pragma unroll
            for (int mi = 0; mi < 4; ++mi)
                a[mi] = *(const bh8*)(Xb + swz(wm * 64 + mi * 16 + (l & 15), kb));
#pragma unroll
            for (int ni = 0; ni < 4; ++ni) {
                int nr = wn * 64 + ni * 16 + (l & 15);
                g[ni] = *(const bh8*)(Gb + swz(nr, kb));
                u[ni] = *(const bh8*)(Ub + swz(nr, kb));
            }
#pragma unroll
            for (int mi = 0; mi < 4; ++mi)
#pragma unroll
                for (int ni = 0; ni < 4; ++ni) {
                    accG[mi][ni] = __builtin_amdgcn_mfma_f32_16x16x32_bf16(a[mi], g[ni], accG[mi][ni], 0, 0, 0);
                    accU[mi][ni] = __builtin_amdgcn_mfma_f32_16x16x32_bf16(a[mi], u[ni], accU[mi][ni], 0, 0, 0);
                }
        }
        __syncthreads();
    }

    // epilogue: gelu(g)*u -> bf16 act, pre-swizzled byte layout
    char* actc = (char*)act;
#pragma unroll
    for (int mi = 0; mi < 4; ++mi) {
#pragma unroll
        for (int i = 0; i < 4; ++i) {
            int r = rt * BM + wm * 64 + mi * 16 + ((l >> 4) << 2) + i;
            size_t rowbase = (size_t)r * (IDIM * 2);
            int rs = (r & 7) << 4;
#pragma unroll
            for (int ni = 0; ni < 4; ++ni) {
                int col = nt * BN + wn * 64 + ni * 16 + (l & 15);
                float gv = accG[mi][ni][i], uv = accU[mi][ni][i];
                float gl = 0.5f * gv * (1.0f + erff(gv * 0.70710678118654752f));
                *(unsigned short*)(actc + rowbase + ((col * 2) ^ rs)) = f2bf(gl * uv);
            }
        }
    }
}

// ============ GEMM2 (round-2 proven body, byte-identical) ============
// 128 rows x 256 cols, waves 2x2 (64x128).
__launch_bounds__(256, 2)
__global__ void gemm2n_kernel(const unsigned short* __restrict__ act,
                              const unsigned short* __restrict__ wdT,
                              const int* __restrict__ offs,
                              const int* __restrict__ row_tok,
                              const float* __restrict__ row_w,
                              float* __restrict__ out) {
    __shared__ char lds[49152];
    char* Xb = lds;          // 128 x 128B
    char* Db = lds + 16384;  // 256 x 128B

    int rt = blockIdx.x >> 3;
    int nt = blockIdx.x & 7;   // 2048 / 256
    int total = offs[NEXP];
    if (rt * BM >= total) return;
    int e = 0;
    while (offs[e + 1] <= rt * BM) e++;

    int tid = threadIdx.x, l = tid & 63, wv = tid >> 6;
    int wm = wv >> 1, wn = wv & 1;

    unsigned srcChunk = ((l & 7) * 16) ^ ((l >> 3) << 4);

    unsigned aoff[4];
#pragma unroll
    for (int i = 0; i < 4; ++i) {
        int r = i * 32 + wv * 8 + (l >> 3);
        aoff[i] = (unsigned)(rt * BM + r) * (IDIM * 2) + (l & 7) * 16;  // act pre-swizzled: linear source
    }
    unsigned doff[8];
#pragma unroll
    for (int i = 0; i < 8; ++i) {
        int r = i * 32 + wv * 8 + (l >> 3);
        doff[i] = ((unsigned)e * HDIM + nt * 256 + r) * (IDIM * 2) + srcChunk;
    }

    f4 acc[4][8];
#pragma unroll
    for (int mi = 0; mi < 4; ++mi)
#pragma unroll
        for (int ni = 0; ni < 8; ++ni) acc[mi][ni] = (f4)0.0f;

    const char* actc = (const char*)act;
    const char* wdc = (const char*)wdT;

    for (int kt = 0; kt < IDIM / BK; ++kt) {
        unsigned kby = kt * 128;
#pragma unroll
        for (int i = 0; i < 4; ++i)
            gload16(actc + (size_t)aoff[i] + kby, Xb + i * 4096 + wv * 1024);
#pragma unroll
        for (int i = 0; i < 8; ++i)
            gload16(wdc + (size_t)doff[i] + kby, Db + i * 4096 + wv * 1024);
        __syncthreads();

#pragma unroll
        for (int ks = 0; ks < 2; ++ks) {
            int kb = ks * 64 + ((l >> 4) << 4);
            bh8 a[4], b[8];
#pragma unroll
            for (int mi = 0; mi < 4; ++mi)
                a[mi] = *(const bh8*)(Xb + swz(wm * 64 + mi * 16 + (l & 15), kb));
#pragma unroll
            for (int ni = 0; ni < 8; ++ni)
                b[ni] = *(const bh8*)(Db + swz(wn * 128 + ni * 16 + (l & 15), kb));
#pragma unroll
            for (int mi = 0; mi < 4; ++mi)
#pragma unroll
                for (int ni = 0; ni < 8; ++ni)
                    acc[mi][ni] = __builtin_amdgcn_mfma_f32_16x16x32_bf16(a[mi], b[ni], acc[mi][ni], 0, 0, 0);
        }
        __syncthreads();
    }

    // epilogue: scale by routing weight, atomic accumulate
#pragma unroll
    for (int mi = 0; mi < 4; ++mi) {
#pragma unroll
        for (int i = 0; i < 4; ++i) {
            int r = rt * BM + wm * 64 + mi * 16 + ((l >> 4) << 2) + i;
            int tok = row_tok[r];
            if (tok < 0) continue;
            float w = row_w[r];
            float* op = out + (size_t)tok * HDIM + nt * 256 + wn * 128 + (l & 15);
#pragma unroll
            for (int ni = 0; ni < 8; ++ni)
                atomicAdd(op + ni * 16, acc[mi][ni][i] * w);
        }
    }
}

// ---------------- launch ----------------
// ws layout:
//   [0,512): counts(128) | cursor(128) | offs(132)
//   512:            row_tok  CAP*4
//   512+CAP*4:      row_w    CAP*4
//   +:              act      CAP*IDIM*2     (41.9 MB)
//   +actB:          hs_bf16  T*H*2          (33.6 MB)
//   +hsB:           wgT      E*I*H*2        (134.2 MB)
//   +wTB:           wuT      E*I*H*2        (134.2 MB)   -> need2 = 344.1 MB
//   +wTB:           wdT      E*I*H*2        (134.2 MB)   -> need3 = 478.3 MB

extern "C" void kernel_launch(void* const* d_in, const int* in_sizes, int n_in,
                              void* d_out, int out_size, void* d_ws, size_t ws_size,
                              hipStream_t stream) {
    const float* hs     = (const float*)d_in[0];
    const float* logits = (const float*)d_in[1];
    const float* scale  = (const float*)d_in[2];
    const float* wg     = (const float*)d_in[3];
    const float* wu     = (const float*)d_in[4];
    const float* wd     = (const float*)d_in[5];
    float* out = (float*)d_out;

    char* ws = (char*)d_ws;
    int*   counts  = (int*)ws;
    int*   cursor  = counts + 32;
    int*   offs    = cursor + 32;
    int*   row_tok = (int*)(ws + 512);
    float* row_w   = (float*)(ws + 512 + (size_t)CAP * 4);

    size_t base = 512 + (size_t)CAP * 8;
    size_t actB = (size_t)CAP * IDIM * 2;
    size_t hsB  = (size_t)T_TOK * HDIM * 2;
    size_t wTB  = (size_t)NEXP * IDIM * HDIM * 2;

    unsigned short* act = (unsigned short*)(ws + base);
    unsigned short* hsb = (unsigned short*)(ws + base + actB);
    unsigned short* wgT = (unsigned short*)(ws + base + actB + hsB);
    unsigned short* wuT = (unsigned short*)(ws + base + actB + hsB + wTB);
    unsigned short* wdT = (unsigned short*)(ws + base + actB + hsB + 2 * wTB);

    size_t need3 = base + actB + hsB + 3 * wTB;
    bool full = (ws_size >= need3);

    hipMemsetAsync(counts, 0, 512, stream);
    hipMemsetAsync(row_tok, 0xFF, (size_t)CAP * 4, stream);
    hipMemsetAsync(out, 0, (size_t)out_size * sizeof(float), stream);

    route_count_kernel<<<T_TOK / 256, 256, 0, stream>>>(logits, counts);
    offsets_kernel<<<1, 64, 0, stream>>>(counts, offs);
    route_scatter_kernel<<<T_TOK / 256, 256, 0, stream>>>(logits, scale, offs, cursor, row_tok, row_w);

    if (full) {
        prep_all<<<CVB + NTB, 256, 0, stream>>>(hs, hsb, wg, wgT, wu, wuT, wd, wdT, 12288);
        gemm1n_kernel<<<MAX_RT * 8, 256, 0, stream>>>(hsb, wgT, wuT, offs, row_tok, act);
        gemm2n_kernel<<<MAX_RT * 8, 256, 0, stream>>>(act, wdT, offs, row_tok, row_w, out);
    } else {
        prep_all<<<CVB + NTB, 256, 0, stream>>>(hs, hsb, wg, wgT, wu, wuT, wd, wdT, 8192);
        gemm1n_kernel<<<MAX_RT * 8, 256, 0, stream>>>(hsb, wgT, wuT, offs, row_tok, act);
        transpose_wd_kernel<<<NTB, 256, 0, stream>>>(wd, wgT);   // reuse wgT region
        gemm2n_kernel<<<MAX_RT * 8, 256, 0, stream>>>(act, wgT, offs, row_tok, row_w, out);
    }
}